// Round 6
// baseline (483.870 us; speedup 1.0000x reference)
//
#include <hip/hip_runtime.h>
#include <hip/hip_bf16.h>
#include <type_traits>

// Problem constants
#define NN 50000
#define EE 800000
#define HH 4
#define DD 64
#define HD 256
#define DIN 128

typedef short bf16x8 __attribute__((ext_vector_type(8)));
typedef float f32x4 __attribute__((ext_vector_type(4)));

__device__ inline ushort f2bf(float x) {
    __hip_bfloat16 b = __float2bfloat16(x);
    return __builtin_bit_cast(ushort, b);
}
__device__ inline float bf2f(ushort u) {
    return __uint_as_float((uint)u << 16);
}

// ---------------- CSR build ----------------

__global__ void hist_kernel(const int* __restrict__ e0, int* __restrict__ cnt, int E) {
    int i = blockIdx.x * 256 + threadIdx.x;
    if (i < E) atomicAdd(&cnt[e0[i]], 1);
}

__global__ __launch_bounds__(1024) void scanA_kernel(const int* __restrict__ cnt,
                                                     int* __restrict__ incl,
                                                     int* __restrict__ tot, int N) {
    __shared__ int buf[2][1024];
    int b = blockIdx.x, t = threadIdx.x;
    int i = b * 1024 + t;
    int v = (i < N) ? cnt[i] : 0;
    buf[0][t] = v;
    __syncthreads();
    int sel = 0;
    for (int off = 1; off < 1024; off <<= 1) {
        int nv = buf[sel][t];
        if (t >= off) nv += buf[sel][t - off];
        buf[sel ^ 1][t] = nv;
        __syncthreads();
        sel ^= 1;
    }
    if (i < N) incl[i] = buf[sel][t];
    if (t == 1023) tot[b] = buf[sel][1023];
}

__global__ void scanB_kernel(int* __restrict__ tot, int nb) {
    if (threadIdx.x == 0) {
        int s = 0;
        for (int b = 0; b < nb; ++b) {
            int v = tot[b];
            tot[b] = s;
            s += v;
        }
    }
}

__global__ void scanC_kernel(const int* __restrict__ incl, const int* __restrict__ tot,
                             const int* __restrict__ cnt, int* __restrict__ rp,
                             int* __restrict__ cur, int N) {
    int i = blockIdx.x * 256 + threadIdx.x;
    if (i == 0) rp[0] = 0;
    if (i < N) {
        int e = incl[i] + tot[i >> 10];
        rp[i + 1] = e;
        cur[i] = e - cnt[i];
    }
}

__global__ void scatter_kernel(const int* __restrict__ e0, const int* __restrict__ e1,
                               int* __restrict__ cur, int* __restrict__ col, int E) {
    int i = blockIdx.x * 256 + threadIdx.x;
    if (i < E) {
        int pos = atomicAdd(&cur[e0[i]], 1);
        col[pos] = e1[i];
    }
}

// ---------------- split f32 -> bf16 hi + lo ----------------

__global__ void split_kernel(const float* __restrict__ src, ushort* __restrict__ hi,
                             ushort* __restrict__ lo, int n4) {
    int i = blockIdx.x * 256 + threadIdx.x;
    if (i < n4) {
        float4 v = ((const float4*)src)[i];
        ushort4 h, l;
        h.x = f2bf(v.x); l.x = f2bf(v.x - bf2f(h.x));
        h.y = f2bf(v.y); l.y = f2bf(v.y - bf2f(h.y));
        h.z = f2bf(v.z); l.z = f2bf(v.z - bf2f(h.z));
        h.w = f2bf(v.w); l.w = f2bf(v.w - bf2f(h.w));
        ((ushort4*)hi)[i] = h;
        ((ushort4*)lo)[i] = l;
    }
}

// ---------------- MFMA GEMM: Y[n][m] = sum_k A[n][k]*W[m][k] + b[m] ----------
// A, W given as bf16 hi/lo splits; 3-term MFMA (hi*hi + hi*lo + lo*hi) in f32
// accumulators gives ~f32 precision. No LDS. Wave computes a 16 x 256 strip.
// Fragment layout (16x16x32): A: row = lane&15, k = (lane>>4)*8 + e (contig 16B)
//                             B: col = lane&15, k = (lane>>4)*8 + e (contig 16B)
//                             D: col = lane&15, row = (lane>>4)*4 + reg

template <int K>
__global__ __launch_bounds__(256) void gemm_mfma(const ushort* __restrict__ Ah,
                                                 const ushort* __restrict__ Al,
                                                 const ushort* __restrict__ Bh,
                                                 const ushort* __restrict__ Bl,
                                                 const float* __restrict__ bias,
                                                 ushort* __restrict__ Y, int Nrows) {
    const int t = threadIdx.x;
    const int w = t >> 6, lane = t & 63;
    const int lg = lane >> 4;   // lane group 0..3
    const int lm = lane & 15;
    const int arow = blockIdx.x * 64 + w * 16 + lm;  // A fragment row

    f32x4 acc[16];
#pragma unroll
    for (int n = 0; n < 16; ++n) acc[n] = (f32x4){0.f, 0.f, 0.f, 0.f};

    for (int k0 = 0; k0 < K; k0 += 32) {
        const int kk = k0 + lg * 8;
        bf16x8 ah = *(const bf16x8*)(Ah + (size_t)arow * K + kk);
        bf16x8 al = *(const bf16x8*)(Al + (size_t)arow * K + kk);
#pragma unroll
        for (int n = 0; n < 16; ++n) {
            const int c = n * 16 + lm;
            bf16x8 bh = *(const bf16x8*)(Bh + (size_t)c * K + kk);
            bf16x8 bl = *(const bf16x8*)(Bl + (size_t)c * K + kk);
            acc[n] = __builtin_amdgcn_mfma_f32_16x16x32_bf16(ah, bh, acc[n], 0, 0, 0);
            acc[n] = __builtin_amdgcn_mfma_f32_16x16x32_bf16(ah, bl, acc[n], 0, 0, 0);
            acc[n] = __builtin_amdgcn_mfma_f32_16x16x32_bf16(al, bh, acc[n], 0, 0, 0);
        }
    }

    const int rbase = blockIdx.x * 64 + w * 16 + lg * 4;
#pragma unroll
    for (int n = 0; n < 16; ++n) {
        const int c = n * 16 + lm;
        const float bv = bias[c];
#pragma unroll
        for (int r = 0; r < 4; ++r) {
            const int rr = rbase + r;
            if (rr < Nrows) Y[(size_t)rr * HD + c] = f2bf(acc[n][r] + bv);
        }
    }
}

// ---------------- per-node attention scores (wave per node, 4 nodes/block) ----

__global__ __launch_bounds__(256) void scores_kernel(const ushort* __restrict__ hbuf,
                                                     const float* __restrict__ att,
                                                     float* __restrict__ sl,
                                                     float* __restrict__ sr) {
    const int t = threadIdx.x;
    const int w = t >> 6;
    const int lane = t & 63;
    const int hh = lane >> 4;
    const int dq = (lane & 15) * 4;  // d offset within head
    const int n = blockIdx.x * 4 + w;

    ushort4 u = *(const ushort4*)(hbuf + (size_t)n * HD + lane * 4);
    float4 al = *(const float4*)(att + hh * 2 * DD + dq);
    float4 ar = *(const float4*)(att + hh * 2 * DD + DD + dq);
    float v0 = bf2f(u.x), v1 = bf2f(u.y), v2 = bf2f(u.z), v3 = bf2f(u.w);

    float p;
    float pl, pr;
    p = v0 * al.x; pl  = p > 0.f ? p : 0.01f * p;
    p = v1 * al.y; pl += p > 0.f ? p : 0.01f * p;
    p = v2 * al.z; pl += p > 0.f ? p : 0.01f * p;
    p = v3 * al.w; pl += p > 0.f ? p : 0.01f * p;
    p = v0 * ar.x; pr  = p > 0.f ? p : 0.01f * p;
    p = v1 * ar.y; pr += p > 0.f ? p : 0.01f * p;
    p = v2 * ar.z; pr += p > 0.f ? p : 0.01f * p;
    p = v3 * ar.w; pr += p > 0.f ? p : 0.01f * p;

#pragma unroll
    for (int m = 1; m < 16; m <<= 1) {
        pl += __shfl_xor(pl, m);
        pr += __shfl_xor(pr, m);
    }
    if ((lane & 15) == 0) {
        sl[n * HH + hh] = pl;
        sr[n * HH + hh] = pr;
    }
}

// ---------------- gather aggregation (one WAVE per node, bf16 payload) -------
// FINAL=false: fused LayerNorm+LeakyReLU epilogue, writes bf16 hi/lo splits.
// FINAL=true : head-mean epilogue (f32 out, N x 64).

template <bool FINAL>
__global__ __launch_bounds__(256) void gather_kernel(const ushort* __restrict__ hbuf,
                                                     const int* __restrict__ rp,
                                                     const int* __restrict__ col,
                                                     const float* __restrict__ sl,
                                                     const float* __restrict__ sr,
                                                     const float* __restrict__ gamma,
                                                     const float* __restrict__ beta,
                                                     float* __restrict__ out,
                                                     ushort* __restrict__ ohi,
                                                     ushort* __restrict__ olo) {
    const int t = threadIdx.x;
    const int w = t >> 6;
    const int lane = t & 63;
    const int hh = lane >> 4;
    const int n = blockIdx.x * 4 + w;

    __shared__ int cb[4][64];
    __shared__ float sv[4][256];

    const int start = rp[n], end = rp[n + 1];
    const float4 sl4 = *(const float4*)(sl + n * HH);

    float acc0 = 0.f, acc1 = 0.f, acc2 = 0.f, acc3 = 0.f;
    float dn0 = 0.f, dn1 = 0.f, dn2 = 0.f, dn3 = 0.f;
    const float C = 0.0078125f;  // 1/(2*64)

    for (int base = start; base < end; base += 64) {
        int m = end - base;
        if (m > 64) m = 64;
        if (lane < m) {
            int src = col[base + lane];
            cb[w][lane] = src;
            float4 sr4 = *(const float4*)(sr + src * HH);
            float e0 = __expf((sl4.x + sr4.x) * C);
            float e1 = __expf((sl4.y + sr4.y) * C);
            float e2 = __expf((sl4.z + sr4.z) * C);
            float e3 = __expf((sl4.w + sr4.w) * C);
            dn0 += e0; dn1 += e1; dn2 += e2; dn3 += e3;
            *(float4*)&sv[w][lane * 4] = make_float4(e0, e1, e2, e3);
        }
        __builtin_amdgcn_wave_barrier();
#pragma unroll 8
        for (int j = 0; j < m; ++j) {
            int src = cb[w][j];
            float s = sv[w][j * 4 + hh];
            ushort4 u = *(const ushort4*)(hbuf + (size_t)src * HD + lane * 4);
            acc0 = fmaf(bf2f(u.x), s, acc0);
            acc1 = fmaf(bf2f(u.y), s, acc1);
            acc2 = fmaf(bf2f(u.z), s, acc2);
            acc3 = fmaf(bf2f(u.w), s, acc3);
        }
        __builtin_amdgcn_wave_barrier();
    }

    // wave-total denominators per head
#pragma unroll
    for (int m2 = 32; m2 > 0; m2 >>= 1) {
        dn0 += __shfl_xor(dn0, m2);
        dn1 += __shfl_xor(dn1, m2);
        dn2 += __shfl_xor(dn2, m2);
        dn3 += __shfl_xor(dn3, m2);
    }
    float den = hh == 0 ? dn0 : hh == 1 ? dn1 : hh == 2 ? dn2 : dn3;
    float inv = 1.f / den;
    float r0 = acc0 * inv, r1 = acc1 * inv, r2 = acc2 * inv, r3 = acc3 * inv;

    if (!FINAL) {
        // fused LayerNorm + LeakyReLU over the 256-elem row held by this wave
        float s = r0 + r1 + r2 + r3;
#pragma unroll
        for (int m2 = 32; m2 > 0; m2 >>= 1) s += __shfl_xor(s, m2);
        float mu = s * (1.f / 256.f);
        float d0 = r0 - mu, d1 = r1 - mu, d2 = r2 - mu, d3 = r3 - mu;
        float vs = d0 * d0 + d1 * d1 + d2 * d2 + d3 * d3;
#pragma unroll
        for (int m2 = 32; m2 > 0; m2 >>= 1) vs += __shfl_xor(vs, m2);
        float rs = rsqrtf(vs * (1.f / 256.f) + 1e-5f);
        float4 g = *(const float4*)(gamma + lane * 4);
        float4 bb = *(const float4*)(beta + lane * 4);
        float y0 = d0 * rs * g.x + bb.x;
        float y1 = d1 * rs * g.y + bb.y;
        float y2 = d2 * rs * g.z + bb.z;
        float y3 = d3 * rs * g.w + bb.w;
        y0 = y0 > 0.f ? y0 : 0.01f * y0;
        y1 = y1 > 0.f ? y1 : 0.01f * y1;
        y2 = y2 > 0.f ? y2 : 0.01f * y2;
        y3 = y3 > 0.f ? y3 : 0.01f * y3;
        ushort4 h, l;
        h.x = f2bf(y0); l.x = f2bf(y0 - bf2f(h.x));
        h.y = f2bf(y1); l.y = f2bf(y1 - bf2f(h.y));
        h.z = f2bf(y2); l.z = f2bf(y2 - bf2f(h.z));
        h.w = f2bf(y3); l.w = f2bf(y3 - bf2f(h.w));
        *(ushort4*)(ohi + (size_t)n * HD + lane * 4) = h;
        *(ushort4*)(olo + (size_t)n * HD + lane * 4) = l;
    } else {
        // head-mean: lanes {c, c+16, c+32, c+48} hold same d-block, diff heads
        r0 += __shfl_xor(r0, 16); r0 += __shfl_xor(r0, 32);
        r1 += __shfl_xor(r1, 16); r1 += __shfl_xor(r1, 32);
        r2 += __shfl_xor(r2, 16); r2 += __shfl_xor(r2, 32);
        r3 += __shfl_xor(r3, 16); r3 += __shfl_xor(r3, 32);
        if (lane < 16) {
            *(float4*)(out + (size_t)n * DD + lane * 4) =
                make_float4(r0 * 0.25f, r1 * 0.25f, r2 * 0.25f, r3 * 0.25f);
        }
    }
}

// ---------------- launch ----------------

extern "C" void kernel_launch(void* const* d_in, const int* in_sizes, int n_in,
                              void* d_out, int out_size, void* d_ws, size_t ws_size,
                              hipStream_t stream) {
    const float* x     = (const float*)d_in[0];
    const int*   ei    = (const int*)d_in[1];   // (2, E): e0 then e1
    const float* W0    = (const float*)d_in[2];
    const float* b0    = (const float*)d_in[3];
    const float* W1    = (const float*)d_in[4];
    const float* b1    = (const float*)d_in[5];
    const float* att0  = (const float*)d_in[6];
    const float* att1  = (const float*)d_in[7];
    const float* gamma = (const float*)d_in[8];
    const float* beta  = (const float*)d_in[9];
    float* out = (float*)d_out;

    const int N = NN, E = EE;

    // workspace layout (~108 MB)
    ushort* ahi = (ushort*)d_ws;                  // N*256 bf16 (LN out hi)
    ushort* alo = ahi + (size_t)N * HD;           // N*256 bf16 (LN out lo)
    ushort* hb0 = alo + (size_t)N * HD;           // N*256 bf16 (h0)
    ushort* hb1 = hb0 + (size_t)N * HD;           // N*256 bf16 (h1); also x-splits
    ushort* xh  = hb1;                            // N*128 (dead before h1 written)
    ushort* xl  = hb1 + (size_t)N * DIN;          // N*128
    ushort* w0h = hb1 + (size_t)N * HD;           // 256*128
    ushort* w0l = w0h + HD * DIN;                 // 256*128
    ushort* w1h = w0l + HD * DIN;                 // 256*256
    ushort* w1l = w1h + HD * HD;                  // 256*256
    float* sl   = (float*)(w1l + HD * HD);        // N*4
    float* sr   = sl + (size_t)N * HH;            // N*4
    int*   cnt  = (int*)(sr + (size_t)N * HH);    // N
    int*   rp   = cnt + N;                        // N+1
    int*   cur  = rp + N + 1;                     // N
    int*   col  = cur + N;                        // E
    int*   incl = col + E;                        // N
    int*   tot  = incl + N;                       // 64

    const int* e0 = ei;
    const int* e1 = ei + E;

    const int NB = (N + 1023) / 1024;  // 49

    // CSR build (same for both layers)
    hipMemsetAsync(cnt, 0, N * sizeof(int), stream);
    hist_kernel<<<(E + 255) / 256, 256, 0, stream>>>(e0, cnt, E);
    scanA_kernel<<<NB, 1024, 0, stream>>>(cnt, incl, tot, N);
    scanB_kernel<<<1, 64, 0, stream>>>(tot, NB);
    scanC_kernel<<<(N + 255) / 256, 256, 0, stream>>>(incl, tot, cnt, rp, cur, N);
    scatter_kernel<<<(E + 255) / 256, 256, 0, stream>>>(e0, e1, cur, col, E);

    // operand splits
    split_kernel<<<(N * DIN / 4 + 255) / 256, 256, 0, stream>>>(x, xh, xl, N * DIN / 4);
    split_kernel<<<(HD * DIN / 4 + 255) / 256, 256, 0, stream>>>(W0, w0h, w0l, HD * DIN / 4);
    split_kernel<<<(HD * HD / 4 + 255) / 256, 256, 0, stream>>>(W1, w1h, w1l, HD * HD / 4);

    const int GB = (N + 63) / 64;  // 782 blocks, 64 rows each

    // layer 0
    gemm_mfma<DIN><<<GB, 256, 0, stream>>>(xh, xl, w0h, w0l, b0, hb0, N);
    scores_kernel<<<N / 4, 256, 0, stream>>>(hb0, att0, sl, sr);
    gather_kernel<false><<<N / 4, 256, 0, stream>>>(hb0, rp, col, sl, sr, gamma, beta,
                                                    nullptr, ahi, alo);

    // layer 1
    gemm_mfma<HD><<<GB, 256, 0, stream>>>(ahi, alo, w1h, w1l, b1, hb1, N);
    scores_kernel<<<N / 4, 256, 0, stream>>>(hb1, att1, sl, sr);
    gather_kernel<true><<<N / 4, 256, 0, stream>>>(hb1, rp, col, sl, sr, gamma, beta,
                                                   out, nullptr, nullptr);
}

// Round 7
// 374.359 us; speedup vs baseline: 1.2925x; 1.2925x over previous
//
#include <hip/hip_runtime.h>
#include <hip/hip_bf16.h>
#include <type_traits>

// Problem constants
#define NN 50000
#define EE 800000
#define HH 4
#define DD 64
#define HD 256
#define DIN 128

typedef short bf16x8 __attribute__((ext_vector_type(8)));
typedef float f32x4 __attribute__((ext_vector_type(4)));

__device__ inline ushort f2bf(float x) {
    __hip_bfloat16 b = __float2bfloat16(x);
    return __builtin_bit_cast(ushort, b);
}
__device__ inline float bf2f(ushort u) {
    return __uint_as_float((uint)u << 16);
}

// async global->LDS, 16B per lane; LDS base must be wave-uniform, global per-lane
__device__ inline void gload16(const ushort* src, ushort* lds_dst) {
    __builtin_amdgcn_global_load_lds(
        (const __attribute__((address_space(1))) void*)src,
        (__attribute__((address_space(3))) void*)lds_dst, 16, 0, 0);
}

// ---------------- CSR build ----------------

__global__ void hist_kernel(const int* __restrict__ e0, int* __restrict__ cnt, int E) {
    int i = blockIdx.x * 256 + threadIdx.x;
    if (i < E) atomicAdd(&cnt[e0[i]], 1);
}

__global__ __launch_bounds__(1024) void scanA_kernel(const int* __restrict__ cnt,
                                                     int* __restrict__ incl,
                                                     int* __restrict__ tot, int N) {
    __shared__ int buf[2][1024];
    int b = blockIdx.x, t = threadIdx.x;
    int i = b * 1024 + t;
    int v = (i < N) ? cnt[i] : 0;
    buf[0][t] = v;
    __syncthreads();
    int sel = 0;
    for (int off = 1; off < 1024; off <<= 1) {
        int nv = buf[sel][t];
        if (t >= off) nv += buf[sel][t - off];
        buf[sel ^ 1][t] = nv;
        __syncthreads();
        sel ^= 1;
    }
    if (i < N) incl[i] = buf[sel][t];
    if (t == 1023) tot[b] = buf[sel][1023];
}

__global__ void scanB_kernel(int* __restrict__ tot, int nb) {
    if (threadIdx.x == 0) {
        int s = 0;
        for (int b = 0; b < nb; ++b) {
            int v = tot[b];
            tot[b] = s;
            s += v;
        }
    }
}

__global__ void scanC_kernel(const int* __restrict__ incl, const int* __restrict__ tot,
                             const int* __restrict__ cnt, int* __restrict__ rp,
                             int* __restrict__ cur, int N) {
    int i = blockIdx.x * 256 + threadIdx.x;
    if (i == 0) rp[0] = 0;
    if (i < N) {
        int e = incl[i] + tot[i >> 10];
        rp[i + 1] = e;
        cur[i] = e - cnt[i];
    }
}

__global__ void scatter_kernel(const int* __restrict__ e0, const int* __restrict__ e1,
                               int* __restrict__ cur, int* __restrict__ col, int E) {
    int i = blockIdx.x * 256 + threadIdx.x;
    if (i < E) {
        int pos = atomicAdd(&cur[e0[i]], 1);
        col[pos] = e1[i];
    }
}

// ---------------- split f32 -> bf16 hi + lo ----------------

__global__ void split_kernel(const float* __restrict__ src, ushort* __restrict__ hi,
                             ushort* __restrict__ lo, int n4) {
    int i = blockIdx.x * 256 + threadIdx.x;
    if (i < n4) {
        float4 v = ((const float4*)src)[i];
        ushort4 h, l;
        h.x = f2bf(v.x); l.x = f2bf(v.x - bf2f(h.x));
        h.y = f2bf(v.y); l.y = f2bf(v.y - bf2f(h.y));
        h.z = f2bf(v.z); l.z = f2bf(v.z - bf2f(h.z));
        h.w = f2bf(v.w); l.w = f2bf(v.w - bf2f(h.w));
        ((ushort4*)hi)[i] = h;
        ((ushort4*)lo)[i] = l;
    }
}

// ---------------- MFMA GEMM: Y[n][m] = sum_k A[n][k]*W[m][k] + b[m] ----------
// A, W as bf16 hi/lo splits; 3-term MFMA (hi*hi + hi*lo + lo*hi), f32 accum.
// Block: 64 rows x 256 cols, 4 waves (wave w = rows w*16..w*16+15), BK=32.
// LDS staged via global_load_lds(16B): layout [kchunk(4)][row][8k] so both the
// linear async-write and the b128 fragment reads are conflict-free.

template <int K>
__global__ __launch_bounds__(256) void gemm_mfma(const ushort* __restrict__ Ah,
                                                 const ushort* __restrict__ Al,
                                                 const ushort* __restrict__ Bh,
                                                 const ushort* __restrict__ Bl,
                                                 const float* __restrict__ bias,
                                                 ushort* __restrict__ Y, int Nrows) {
    __shared__ ushort lAh[4][64][8];    // 4 KB  [kchunk][row][8k]
    __shared__ ushort lAl[4][64][8];    // 4 KB
    __shared__ ushort lBh[4][256][8];   // 16 KB [kchunk][col][8k]
    __shared__ ushort lBl[4][256][8];   // 16 KB

    const int t = threadIdx.x;
    const int w = t >> 6, lane = t & 63;
    const int lg = lane >> 4;   // k-chunk group 0..3
    const int lm = lane & 15;
    const int row0 = blockIdx.x * 64;

    f32x4 acc[16];
#pragma unroll
    for (int n = 0; n < 16; ++n) acc[n] = (f32x4){0.f, 0.f, 0.f, 0.f};

    for (int ks = 0; ks < K / 32; ++ks) {
        const int k0 = ks * 32;
        if (ks) __syncthreads();  // previous tile's reads complete
        // stage A: wave w fills kchunk w (rows 0..63 via lane)
        gload16(Ah + (size_t)(row0 + lane) * K + k0 + w * 8, &lAh[w][0][0]);
        gload16(Al + (size_t)(row0 + lane) * K + k0 + w * 8, &lAl[w][0][0]);
        // stage B: wave w fills kchunk w, col blocks j2*64+lane
#pragma unroll
        for (int j2 = 0; j2 < 4; ++j2) {
            gload16(Bh + (size_t)(j2 * 64 + lane) * K + k0 + w * 8, &lBh[w][j2 * 64][0]);
            gload16(Bl + (size_t)(j2 * 64 + lane) * K + k0 + w * 8, &lBl[w][j2 * 64][0]);
        }
        asm volatile("s_waitcnt vmcnt(0)");
        __syncthreads();

        bf16x8 ah = *(const bf16x8*)&lAh[lg][w * 16 + lm][0];
        bf16x8 al = *(const bf16x8*)&lAl[lg][w * 16 + lm][0];
#pragma unroll
        for (int n = 0; n < 16; ++n) {
            bf16x8 bh = *(const bf16x8*)&lBh[lg][n * 16 + lm][0];
            bf16x8 bl = *(const bf16x8*)&lBl[lg][n * 16 + lm][0];
            acc[n] = __builtin_amdgcn_mfma_f32_16x16x32_bf16(ah, bh, acc[n], 0, 0, 0);
            acc[n] = __builtin_amdgcn_mfma_f32_16x16x32_bf16(ah, bl, acc[n], 0, 0, 0);
            acc[n] = __builtin_amdgcn_mfma_f32_16x16x32_bf16(al, bh, acc[n], 0, 0, 0);
        }
    }

    // D layout: col = lm, row = lg*4 + r within the wave's 16x16 tile
    const int rbase = row0 + w * 16 + lg * 4;
#pragma unroll
    for (int n = 0; n < 16; ++n) {
        const int c = n * 16 + lm;
        const float bv = bias[c];
#pragma unroll
        for (int r = 0; r < 4; ++r) {
            const int rr = rbase + r;
            if (rr < Nrows) Y[(size_t)rr * HD + c] = f2bf(acc[n][r] + bv);
        }
    }
}

// ---------------- per-node attention scores (wave per node, 4 nodes/block) ----

__global__ __launch_bounds__(256) void scores_kernel(const ushort* __restrict__ hbuf,
                                                     const float* __restrict__ att,
                                                     float* __restrict__ sl,
                                                     float* __restrict__ sr) {
    const int t = threadIdx.x;
    const int w = t >> 6;
    const int lane = t & 63;
    const int hh = lane >> 4;
    const int dq = (lane & 15) * 4;  // d offset within head
    const int n = blockIdx.x * 4 + w;

    ushort4 u = *(const ushort4*)(hbuf + (size_t)n * HD + lane * 4);
    float4 al = *(const float4*)(att + hh * 2 * DD + dq);
    float4 ar = *(const float4*)(att + hh * 2 * DD + DD + dq);
    float v0 = bf2f(u.x), v1 = bf2f(u.y), v2 = bf2f(u.z), v3 = bf2f(u.w);

    float p;
    float pl, pr;
    p = v0 * al.x; pl  = p > 0.f ? p : 0.01f * p;
    p = v1 * al.y; pl += p > 0.f ? p : 0.01f * p;
    p = v2 * al.z; pl += p > 0.f ? p : 0.01f * p;
    p = v3 * al.w; pl += p > 0.f ? p : 0.01f * p;
    p = v0 * ar.x; pr  = p > 0.f ? p : 0.01f * p;
    p = v1 * ar.y; pr += p > 0.f ? p : 0.01f * p;
    p = v2 * ar.z; pr += p > 0.f ? p : 0.01f * p;
    p = v3 * ar.w; pr += p > 0.f ? p : 0.01f * p;

#pragma unroll
    for (int m = 1; m < 16; m <<= 1) {
        pl += __shfl_xor(pl, m);
        pr += __shfl_xor(pr, m);
    }
    if ((lane & 15) == 0) {
        sl[n * HH + hh] = pl;
        sr[n * HH + hh] = pr;
    }
}

// ---------------- gather aggregation (one WAVE per node, bf16 payload) -------
// FINAL=false: fused LayerNorm+LeakyReLU epilogue, writes bf16 hi/lo splits.
// FINAL=true : head-mean epilogue (f32 out, N x 64).

template <bool FINAL>
__global__ __launch_bounds__(256) void gather_kernel(const ushort* __restrict__ hbuf,
                                                     const int* __restrict__ rp,
                                                     const int* __restrict__ col,
                                                     const float* __restrict__ sl,
                                                     const float* __restrict__ sr,
                                                     const float* __restrict__ gamma,
                                                     const float* __restrict__ beta,
                                                     float* __restrict__ out,
                                                     ushort* __restrict__ ohi,
                                                     ushort* __restrict__ olo) {
    const int t = threadIdx.x;
    const int w = t >> 6;
    const int lane = t & 63;
    const int hh = lane >> 4;
    const int n = blockIdx.x * 4 + w;

    __shared__ int cb[4][64];
    __shared__ float sv[4][256];

    const int start = rp[n], end = rp[n + 1];
    const float4 sl4 = *(const float4*)(sl + n * HH);

    float acc0 = 0.f, acc1 = 0.f, acc2 = 0.f, acc3 = 0.f;
    float dn0 = 0.f, dn1 = 0.f, dn2 = 0.f, dn3 = 0.f;
    const float C = 0.0078125f;  // 1/(2*64)

    for (int base = start; base < end; base += 64) {
        int m = end - base;
        if (m > 64) m = 64;
        if (lane < m) {
            int src = col[base + lane];
            cb[w][lane] = src;
            float4 sr4 = *(const float4*)(sr + src * HH);
            float e0 = __expf((sl4.x + sr4.x) * C);
            float e1 = __expf((sl4.y + sr4.y) * C);
            float e2 = __expf((sl4.z + sr4.z) * C);
            float e3 = __expf((sl4.w + sr4.w) * C);
            dn0 += e0; dn1 += e1; dn2 += e2; dn3 += e3;
            *(float4*)&sv[w][lane * 4] = make_float4(e0, e1, e2, e3);
        }
        __builtin_amdgcn_wave_barrier();
#pragma unroll 8
        for (int j = 0; j < m; ++j) {
            int src = cb[w][j];
            float s = sv[w][j * 4 + hh];
            ushort4 u = *(const ushort4*)(hbuf + (size_t)src * HD + lane * 4);
            acc0 = fmaf(bf2f(u.x), s, acc0);
            acc1 = fmaf(bf2f(u.y), s, acc1);
            acc2 = fmaf(bf2f(u.z), s, acc2);
            acc3 = fmaf(bf2f(u.w), s, acc3);
        }
        __builtin_amdgcn_wave_barrier();
    }

    // wave-total denominators per head
#pragma unroll
    for (int m2 = 32; m2 > 0; m2 >>= 1) {
        dn0 += __shfl_xor(dn0, m2);
        dn1 += __shfl_xor(dn1, m2);
        dn2 += __shfl_xor(dn2, m2);
        dn3 += __shfl_xor(dn3, m2);
    }
    float den = hh == 0 ? dn0 : hh == 1 ? dn1 : hh == 2 ? dn2 : dn3;
    float inv = 1.f / den;
    float r0 = acc0 * inv, r1 = acc1 * inv, r2 = acc2 * inv, r3 = acc3 * inv;

    if (!FINAL) {
        // fused LayerNorm + LeakyReLU over the 256-elem row held by this wave
        float s = r0 + r1 + r2 + r3;
#pragma unroll
        for (int m2 = 32; m2 > 0; m2 >>= 1) s += __shfl_xor(s, m2);
        float mu = s * (1.f / 256.f);
        float d0 = r0 - mu, d1 = r1 - mu, d2 = r2 - mu, d3 = r3 - mu;
        float vs = d0 * d0 + d1 * d1 + d2 * d2 + d3 * d3;
#pragma unroll
        for (int m2 = 32; m2 > 0; m2 >>= 1) vs += __shfl_xor(vs, m2);
        float rs = rsqrtf(vs * (1.f / 256.f) + 1e-5f);
        float4 g = *(const float4*)(gamma + lane * 4);
        float4 bb = *(const float4*)(beta + lane * 4);
        float y0 = d0 * rs * g.x + bb.x;
        float y1 = d1 * rs * g.y + bb.y;
        float y2 = d2 * rs * g.z + bb.z;
        float y3 = d3 * rs * g.w + bb.w;
        y0 = y0 > 0.f ? y0 : 0.01f * y0;
        y1 = y1 > 0.f ? y1 : 0.01f * y1;
        y2 = y2 > 0.f ? y2 : 0.01f * y2;
        y3 = y3 > 0.f ? y3 : 0.01f * y3;
        ushort4 h, l;
        h.x = f2bf(y0); l.x = f2bf(y0 - bf2f(h.x));
        h.y = f2bf(y1); l.y = f2bf(y1 - bf2f(h.y));
        h.z = f2bf(y2); l.z = f2bf(y2 - bf2f(h.z));
        h.w = f2bf(y3); l.w = f2bf(y3 - bf2f(h.w));
        *(ushort4*)(ohi + (size_t)n * HD + lane * 4) = h;
        *(ushort4*)(olo + (size_t)n * HD + lane * 4) = l;
    } else {
        // head-mean: lanes {c, c+16, c+32, c+48} hold same d-block, diff heads
        r0 += __shfl_xor(r0, 16); r0 += __shfl_xor(r0, 32);
        r1 += __shfl_xor(r1, 16); r1 += __shfl_xor(r1, 32);
        r2 += __shfl_xor(r2, 16); r2 += __shfl_xor(r2, 32);
        r3 += __shfl_xor(r3, 16); r3 += __shfl_xor(r3, 32);
        if (lane < 16) {
            *(float4*)(out + (size_t)n * DD + lane * 4) =
                make_float4(r0 * 0.25f, r1 * 0.25f, r2 * 0.25f, r3 * 0.25f);
        }
    }
}

// ---------------- launch ----------------

extern "C" void kernel_launch(void* const* d_in, const int* in_sizes, int n_in,
                              void* d_out, int out_size, void* d_ws, size_t ws_size,
                              hipStream_t stream) {
    const float* x     = (const float*)d_in[0];
    const int*   ei    = (const int*)d_in[1];   // (2, E): e0 then e1
    const float* W0    = (const float*)d_in[2];
    const float* b0    = (const float*)d_in[3];
    const float* W1    = (const float*)d_in[4];
    const float* b1    = (const float*)d_in[5];
    const float* att0  = (const float*)d_in[6];
    const float* att1  = (const float*)d_in[7];
    const float* gamma = (const float*)d_in[8];
    const float* beta  = (const float*)d_in[9];
    float* out = (float*)d_out;

    const int N = NN, E = EE;

    // workspace layout (~108 MB)
    ushort* ahi = (ushort*)d_ws;                  // N*256 bf16 (LN out hi)
    ushort* alo = ahi + (size_t)N * HD;           // N*256 bf16 (LN out lo)
    ushort* hb0 = alo + (size_t)N * HD;           // N*256 bf16 (h0)
    ushort* hb1 = hb0 + (size_t)N * HD;           // N*256 bf16 (h1); also x-splits
    ushort* xh  = hb1;                            // N*128 (dead before h1 written)
    ushort* xl  = hb1 + (size_t)N * DIN;          // N*128
    ushort* w0h = hb1 + (size_t)N * HD;           // 256*128
    ushort* w0l = w0h + HD * DIN;                 // 256*128
    ushort* w1h = w0l + HD * DIN;                 // 256*256
    ushort* w1l = w1h + HD * HD;                  // 256*256
    float* sl   = (float*)(w1l + HD * HD);        // N*4
    float* sr   = sl + (size_t)N * HH;            // N*4
    int*   cnt  = (int*)(sr + (size_t)N * HH);    // N
    int*   rp   = cnt + N;                        // N+1
    int*   cur  = rp + N + 1;                     // N
    int*   col  = cur + N;                        // E
    int*   incl = col + E;                        // N
    int*   tot  = incl + N;                       // 64

    const int* e0 = ei;
    const int* e1 = ei + E;

    const int NB = (N + 1023) / 1024;  // 49

    // CSR build (same for both layers)
    hipMemsetAsync(cnt, 0, N * sizeof(int), stream);
    hist_kernel<<<(E + 255) / 256, 256, 0, stream>>>(e0, cnt, E);
    scanA_kernel<<<NB, 1024, 0, stream>>>(cnt, incl, tot, N);
    scanB_kernel<<<1, 64, 0, stream>>>(tot, NB);
    scanC_kernel<<<(N + 255) / 256, 256, 0, stream>>>(incl, tot, cnt, rp, cur, N);
    scatter_kernel<<<(E + 255) / 256, 256, 0, stream>>>(e0, e1, cur, col, E);

    // operand splits
    split_kernel<<<(N * DIN / 4 + 255) / 256, 256, 0, stream>>>(x, xh, xl, N * DIN / 4);
    split_kernel<<<(HD * DIN / 4 + 255) / 256, 256, 0, stream>>>(W0, w0h, w0l, HD * DIN / 4);
    split_kernel<<<(HD * HD / 4 + 255) / 256, 256, 0, stream>>>(W1, w1h, w1l, HD * HD / 4);

    const int GB = (N + 63) / 64;  // 782 blocks, 64 rows each

    // layer 0
    gemm_mfma<DIN><<<GB, 256, 0, stream>>>(xh, xl, w0h, w0l, b0, hb0, N);
    scores_kernel<<<N / 4, 256, 0, stream>>>(hb0, att0, sl, sr);
    gather_kernel<false><<<N / 4, 256, 0, stream>>>(hb0, rp, col, sl, sr, gamma, beta,
                                                    nullptr, ahi, alo);

    // layer 1
    gemm_mfma<HD><<<GB, 256, 0, stream>>>(ahi, alo, w1h, w1l, b1, hb1, N);
    scores_kernel<<<N / 4, 256, 0, stream>>>(hb1, att1, sl, sr);
    gather_kernel<true><<<N / 4, 256, 0, stream>>>(hb1, rp, col, sl, sr, gamma, beta,
                                                   out, nullptr, nullptr);
}

// Round 8
// 332.292 us; speedup vs baseline: 1.4562x; 1.1266x over previous
//
#include <hip/hip_runtime.h>
#include <hip/hip_bf16.h>
#include <type_traits>

// Problem constants
#define NN 50000
#define EE 800000
#define HH 4
#define DD 64
#define HD 256
#define DIN 128

typedef short bf16x8 __attribute__((ext_vector_type(8)));
typedef float f32x4 __attribute__((ext_vector_type(4)));

__device__ inline ushort f2bf(float x) {
    __hip_bfloat16 b = __float2bfloat16(x);
    return __builtin_bit_cast(ushort, b);
}
__device__ inline float bf2f(ushort u) {
    return __uint_as_float((uint)u << 16);
}

// async global->LDS, 16B per lane; LDS base must be wave-uniform, global per-lane
__device__ inline void gload16(const ushort* src, ushort* lds_dst) {
    __builtin_amdgcn_global_load_lds(
        (const __attribute__((address_space(1))) void*)src,
        (__attribute__((address_space(3))) void*)lds_dst, 16, 0, 0);
}

// ---------------- CSR build ----------------

__global__ void hist_kernel(const int* __restrict__ e0, int* __restrict__ cnt, int E) {
    int i = blockIdx.x * 256 + threadIdx.x;
    if (i < E) atomicAdd(&cnt[e0[i]], 1);
}

__global__ __launch_bounds__(1024) void scanA_kernel(const int* __restrict__ cnt,
                                                     int* __restrict__ incl,
                                                     int* __restrict__ tot, int N) {
    __shared__ int buf[2][1024];
    int b = blockIdx.x, t = threadIdx.x;
    int i = b * 1024 + t;
    int v = (i < N) ? cnt[i] : 0;
    buf[0][t] = v;
    __syncthreads();
    int sel = 0;
    for (int off = 1; off < 1024; off <<= 1) {
        int nv = buf[sel][t];
        if (t >= off) nv += buf[sel][t - off];
        buf[sel ^ 1][t] = nv;
        __syncthreads();
        sel ^= 1;
    }
    if (i < N) incl[i] = buf[sel][t];
    if (t == 1023) tot[b] = buf[sel][1023];
}

__global__ void scanB_kernel(int* __restrict__ tot, int nb) {
    if (threadIdx.x == 0) {
        int s = 0;
        for (int b = 0; b < nb; ++b) {
            int v = tot[b];
            tot[b] = s;
            s += v;
        }
    }
}

__global__ void scanC_kernel(const int* __restrict__ incl, const int* __restrict__ tot,
                             const int* __restrict__ cnt, int* __restrict__ rp,
                             int* __restrict__ cur, int N) {
    int i = blockIdx.x * 256 + threadIdx.x;
    if (i == 0) rp[0] = 0;
    if (i < N) {
        int e = incl[i] + tot[i >> 10];
        rp[i + 1] = e;
        cur[i] = e - cnt[i];
    }
}

__global__ void scatter_kernel(const int* __restrict__ e0, const int* __restrict__ e1,
                               int* __restrict__ cur, int* __restrict__ col, int E) {
    int i = blockIdx.x * 256 + threadIdx.x;
    if (i < E) {
        int pos = atomicAdd(&cur[e0[i]], 1);
        col[pos] = e1[i];
    }
}

// ---------------- split f32 -> bf16 hi + lo ----------------

__global__ void split_kernel(const float* __restrict__ src, ushort* __restrict__ hi,
                             ushort* __restrict__ lo, int n4) {
    int i = blockIdx.x * 256 + threadIdx.x;
    if (i < n4) {
        float4 v = ((const float4*)src)[i];
        ushort4 h, l;
        h.x = f2bf(v.x); l.x = f2bf(v.x - bf2f(h.x));
        h.y = f2bf(v.y); l.y = f2bf(v.y - bf2f(h.y));
        h.z = f2bf(v.z); l.z = f2bf(v.z - bf2f(h.z));
        h.w = f2bf(v.w); l.w = f2bf(v.w - bf2f(h.w));
        ((ushort4*)hi)[i] = h;
        ((ushort4*)lo)[i] = l;
    }
}

// ---------------- MFMA GEMM + fused right-score epilogue ----------------
// Y[n][m] = sum_k A[n][k]*W[m][k] + b[m]   (3-term hi/lo MFMA, f32 accum)
// bw[n][h] = exp( (sum_d lrelu(Y[n][h*64+d]*att_r[h][d])) / 128 )
// Block: 64 rows x 256 cols, 4 waves, BK=32, double-buffered LDS (2x40KB).
// LDS layout [kchunk(4)][row][8k]: linear for global_load_lds, uniform-bank
// for ds_read_b128 fragments.

template <int K>
__global__ __launch_bounds__(256) void gemm_mfma(const ushort* __restrict__ Ah,
                                                 const ushort* __restrict__ Al,
                                                 const ushort* __restrict__ Bh,
                                                 const ushort* __restrict__ Bl,
                                                 const float* __restrict__ bias,
                                                 const float* __restrict__ att,
                                                 ushort* __restrict__ Y,
                                                 float* __restrict__ bw,
                                                 int Nrows) {
    __shared__ ushort sh[2][20480];  // per buf: Ah[4][64][8] Al[..] Bh[4][256][8] Bl[..]

    const int t = threadIdx.x;
    const int w = t >> 6, lane = t & 63;
    const int lg = lane >> 4;
    const int lm = lane & 15;
    const int row0 = blockIdx.x * 64;

    f32x4 acc[16];
#pragma unroll
    for (int n = 0; n < 16; ++n) acc[n] = (f32x4){0.f, 0.f, 0.f, 0.f};

    auto STAGE = [&](int b, int ks) {
        const int k0 = ks * 32;
        ushort* base = sh[b];
        gload16(Ah + (size_t)(row0 + lane) * K + k0 + w * 8, base + w * 512);
        gload16(Al + (size_t)(row0 + lane) * K + k0 + w * 8, base + 2048 + w * 512);
#pragma unroll
        for (int j2 = 0; j2 < 4; ++j2) {
            gload16(Bh + (size_t)(j2 * 64 + lane) * K + k0 + w * 8,
                    base + 4096 + w * 2048 + j2 * 512);
            gload16(Bl + (size_t)(j2 * 64 + lane) * K + k0 + w * 8,
                    base + 12288 + w * 2048 + j2 * 512);
        }
    };
    auto COMPUTE = [&](int b) {
        ushort* base = sh[b];
        bf16x8 ah = *(const bf16x8*)(base + lg * 512 + (w * 16 + lm) * 8);
        bf16x8 al = *(const bf16x8*)(base + 2048 + lg * 512 + (w * 16 + lm) * 8);
#pragma unroll
        for (int n = 0; n < 16; ++n) {
            bf16x8 bh = *(const bf16x8*)(base + 4096 + lg * 2048 + (n * 16 + lm) * 8);
            bf16x8 bl = *(const bf16x8*)(base + 12288 + lg * 2048 + (n * 16 + lm) * 8);
            acc[n] = __builtin_amdgcn_mfma_f32_16x16x32_bf16(ah, bh, acc[n], 0, 0, 0);
            acc[n] = __builtin_amdgcn_mfma_f32_16x16x32_bf16(ah, bl, acc[n], 0, 0, 0);
            acc[n] = __builtin_amdgcn_mfma_f32_16x16x32_bf16(al, bh, acc[n], 0, 0, 0);
        }
    };

    constexpr int NT = K / 32;
    STAGE(0, 0);
    asm volatile("s_waitcnt vmcnt(0)" ::: "memory");
    __syncthreads();
    int cur = 0;
#pragma unroll
    for (int ks = 0; ks < NT - 1; ++ks) {
        STAGE(cur ^ 1, ks + 1);   // prefetch next tile (overlaps MFMA below)
        COMPUTE(cur);
        asm volatile("s_waitcnt vmcnt(0)" ::: "memory");
        __syncthreads();
        cur ^= 1;
    }
    COMPUTE(cur);

    // ---- epilogue: bias, bf16 store, fused right-scores ----
    const int rbase = row0 + w * 16 + lg * 4;
    float attr[16];
#pragma unroll
    for (int n = 0; n < 16; ++n)
        attr[n] = att[(n >> 2) * 128 + 64 + (n & 3) * 16 + lm];  // att_r at col n*16+lm
#pragma unroll
    for (int n = 0; n < 16; ++n) {
        const float bv = bias[n * 16 + lm];
        acc[n][0] += bv; acc[n][1] += bv; acc[n][2] += bv; acc[n][3] += bv;
    }
#pragma unroll
    for (int n = 0; n < 16; ++n) {
        const int c = n * 16 + lm;
#pragma unroll
        for (int r = 0; r < 4; ++r) {
            const int rr = rbase + r;
            if (rr < Nrows) Y[(size_t)rr * HD + c] = f2bf(acc[n][r]);
        }
    }
    // per-row per-head s_r = sum lrelu(y*att_r); b = exp(s_r/128)
#pragma unroll
    for (int r = 0; r < 4; ++r) {
        float s0 = 0.f, s1 = 0.f, s2 = 0.f, s3 = 0.f;
#pragma unroll
        for (int n = 0; n < 16; ++n) {
            float p = acc[n][r] * attr[n];
            p = p > 0.f ? p : 0.01f * p;
            if ((n >> 2) == 0) s0 += p;
            else if ((n >> 2) == 1) s1 += p;
            else if ((n >> 2) == 2) s2 += p;
            else s3 += p;
        }
#pragma unroll
        for (int mm = 1; mm < 16; mm <<= 1) {
            s0 += __shfl_xor(s0, mm);
            s1 += __shfl_xor(s1, mm);
            s2 += __shfl_xor(s2, mm);
            s3 += __shfl_xor(s3, mm);
        }
        const int rr = rbase + r;
        if (lm < 4 && rr < Nrows) {
            float sv = lm == 0 ? s0 : lm == 1 ? s1 : lm == 2 ? s2 : s3;
            bw[rr * 4 + lm] = __expf(sv * 0.0078125f);  // 1/(2*64)
        }
    }
}

// ---------------- gather aggregation (one WAVE per node, bf16 payload) -------
// Separable scores: result = (sum_src b[src]*h[src]) / (sum_src b[src]);
// b[src] precomputed by the GEMM epilogue. No exp here.
// FINAL=false: fused LayerNorm+LeakyReLU epilogue, writes bf16 hi/lo splits.
// FINAL=true : head-mean epilogue (f32 out, N x 64).

template <bool FINAL>
__global__ __launch_bounds__(256) void gather_kernel(const ushort* __restrict__ hbuf,
                                                     const int* __restrict__ rp,
                                                     const int* __restrict__ col,
                                                     const float* __restrict__ bw,
                                                     const float* __restrict__ gamma,
                                                     const float* __restrict__ beta,
                                                     float* __restrict__ out,
                                                     ushort* __restrict__ ohi,
                                                     ushort* __restrict__ olo) {
    const int t = threadIdx.x;
    const int w = t >> 6;
    const int lane = t & 63;
    const int hh = lane >> 4;
    const int n = blockIdx.x * 4 + w;

    __shared__ int cb[4][64];
    __shared__ float sv[4][256];

    const int start = rp[n], end = rp[n + 1];

    float acc0 = 0.f, acc1 = 0.f, acc2 = 0.f, acc3 = 0.f;
    float dn0 = 0.f, dn1 = 0.f, dn2 = 0.f, dn3 = 0.f;

    for (int base = start; base < end; base += 64) {
        int m = end - base;
        if (m > 64) m = 64;
        if (lane < m) {
            int src = col[base + lane];
            cb[w][lane] = src;
            float4 b4 = *(const float4*)(bw + src * 4);
            dn0 += b4.x; dn1 += b4.y; dn2 += b4.z; dn3 += b4.w;
            *(float4*)&sv[w][lane * 4] = b4;
        }
        __builtin_amdgcn_wave_barrier();
#pragma unroll 8
        for (int j = 0; j < m; ++j) {
            int src = cb[w][j];
            float s = sv[w][j * 4 + hh];
            ushort4 u = *(const ushort4*)(hbuf + (size_t)src * HD + lane * 4);
            acc0 = fmaf(bf2f(u.x), s, acc0);
            acc1 = fmaf(bf2f(u.y), s, acc1);
            acc2 = fmaf(bf2f(u.z), s, acc2);
            acc3 = fmaf(bf2f(u.w), s, acc3);
        }
        __builtin_amdgcn_wave_barrier();
    }

    // wave-total denominators per head
#pragma unroll
    for (int m2 = 32; m2 > 0; m2 >>= 1) {
        dn0 += __shfl_xor(dn0, m2);
        dn1 += __shfl_xor(dn1, m2);
        dn2 += __shfl_xor(dn2, m2);
        dn3 += __shfl_xor(dn3, m2);
    }
    float den = hh == 0 ? dn0 : hh == 1 ? dn1 : hh == 2 ? dn2 : dn3;
    float inv = 1.f / den;
    float r0 = acc0 * inv, r1 = acc1 * inv, r2 = acc2 * inv, r3 = acc3 * inv;

    if (!FINAL) {
        // fused LayerNorm + LeakyReLU over the 256-elem row held by this wave
        float s = r0 + r1 + r2 + r3;
#pragma unroll
        for (int m2 = 32; m2 > 0; m2 >>= 1) s += __shfl_xor(s, m2);
        float mu = s * (1.f / 256.f);
        float d0 = r0 - mu, d1 = r1 - mu, d2 = r2 - mu, d3 = r3 - mu;
        float vs = d0 * d0 + d1 * d1 + d2 * d2 + d3 * d3;
#pragma unroll
        for (int m2 = 32; m2 > 0; m2 >>= 1) vs += __shfl_xor(vs, m2);
        float rs = rsqrtf(vs * (1.f / 256.f) + 1e-5f);
        float4 g = *(const float4*)(gamma + lane * 4);
        float4 bb = *(const float4*)(beta + lane * 4);
        float y0 = d0 * rs * g.x + bb.x;
        float y1 = d1 * rs * g.y + bb.y;
        float y2 = d2 * rs * g.z + bb.z;
        float y3 = d3 * rs * g.w + bb.w;
        y0 = y0 > 0.f ? y0 : 0.01f * y0;
        y1 = y1 > 0.f ? y1 : 0.01f * y1;
        y2 = y2 > 0.f ? y2 : 0.01f * y2;
        y3 = y3 > 0.f ? y3 : 0.01f * y3;
        ushort4 h, l;
        h.x = f2bf(y0); l.x = f2bf(y0 - bf2f(h.x));
        h.y = f2bf(y1); l.y = f2bf(y1 - bf2f(h.y));
        h.z = f2bf(y2); l.z = f2bf(y2 - bf2f(h.z));
        h.w = f2bf(y3); l.w = f2bf(y3 - bf2f(h.w));
        *(ushort4*)(ohi + (size_t)n * HD + lane * 4) = h;
        *(ushort4*)(olo + (size_t)n * HD + lane * 4) = l;
    } else {
        // head-mean: lanes {c, c+16, c+32, c+48} hold same d-block, diff heads
        r0 += __shfl_xor(r0, 16); r0 += __shfl_xor(r0, 32);
        r1 += __shfl_xor(r1, 16); r1 += __shfl_xor(r1, 32);
        r2 += __shfl_xor(r2, 16); r2 += __shfl_xor(r2, 32);
        r3 += __shfl_xor(r3, 16); r3 += __shfl_xor(r3, 32);
        if (lane < 16) {
            *(float4*)(out + (size_t)n * DD + lane * 4) =
                make_float4(r0 * 0.25f, r1 * 0.25f, r2 * 0.25f, r3 * 0.25f);
        }
    }
}

// ---------------- launch ----------------

extern "C" void kernel_launch(void* const* d_in, const int* in_sizes, int n_in,
                              void* d_out, int out_size, void* d_ws, size_t ws_size,
                              hipStream_t stream) {
    const float* x     = (const float*)d_in[0];
    const int*   ei    = (const int*)d_in[1];   // (2, E): e0 then e1
    const float* W0    = (const float*)d_in[2];
    const float* b0    = (const float*)d_in[3];
    const float* W1    = (const float*)d_in[4];
    const float* b1    = (const float*)d_in[5];
    const float* att0  = (const float*)d_in[6];
    const float* att1  = (const float*)d_in[7];
    const float* gamma = (const float*)d_in[8];
    const float* beta  = (const float*)d_in[9];
    float* out = (float*)d_out;

    const int N = NN, E = EE;

    // workspace layout (~108 MB)
    ushort* ahi = (ushort*)d_ws;                  // N*256 bf16 (LN out hi)
    ushort* alo = ahi + (size_t)N * HD;           // N*256 bf16 (LN out lo)
    ushort* hb0 = alo + (size_t)N * HD;           // N*256 bf16 (h0)
    ushort* hb1 = hb0 + (size_t)N * HD;           // N*256 bf16 (h1); also x-splits
    ushort* xh  = hb1;                            // N*128 (dead before h1 written)
    ushort* xl  = hb1 + (size_t)N * DIN;          // N*128
    ushort* w0h = hb1 + (size_t)N * HD;           // 256*128
    ushort* w0l = w0h + HD * DIN;                 // 256*128
    ushort* w1h = w0l + HD * DIN;                 // 256*256
    ushort* w1l = w1h + HD * HD;                  // 256*256
    float* bw   = (float*)(w1l + HD * HD);        // N*4 (per-node per-head exp(s_r/128))
    int*   cnt  = (int*)(bw + (size_t)N * HH);    // N
    int*   rp   = cnt + N;                        // N+1
    int*   cur  = rp + N + 1;                     // N
    int*   col  = cur + N;                        // E
    int*   incl = col + E;                        // N
    int*   tot  = incl + N;                       // 64

    const int* e0 = ei;
    const int* e1 = ei + E;

    const int NB = (N + 1023) / 1024;  // 49

    // CSR build (same for both layers)
    hipMemsetAsync(cnt, 0, N * sizeof(int), stream);
    hist_kernel<<<(E + 255) / 256, 256, 0, stream>>>(e0, cnt, E);
    scanA_kernel<<<NB, 1024, 0, stream>>>(cnt, incl, tot, N);
    scanB_kernel<<<1, 64, 0, stream>>>(tot, NB);
    scanC_kernel<<<(N + 255) / 256, 256, 0, stream>>>(incl, tot, cnt, rp, cur, N);
    scatter_kernel<<<(E + 255) / 256, 256, 0, stream>>>(e0, e1, cur, col, E);

    // operand splits
    split_kernel<<<(N * DIN / 4 + 255) / 256, 256, 0, stream>>>(x, xh, xl, N * DIN / 4);
    split_kernel<<<(HD * DIN / 4 + 255) / 256, 256, 0, stream>>>(W0, w0h, w0l, HD * DIN / 4);
    split_kernel<<<(HD * HD / 4 + 255) / 256, 256, 0, stream>>>(W1, w1h, w1l, HD * HD / 4);

    const int GB = (N + 63) / 64;  // 782 blocks, 64 rows each

    // layer 0
    gemm_mfma<DIN><<<GB, 256, 0, stream>>>(xh, xl, w0h, w0l, b0, att0, hb0, bw, N);
    gather_kernel<false><<<N / 4, 256, 0, stream>>>(hb0, rp, col, bw, gamma, beta,
                                                    nullptr, ahi, alo);

    // layer 1
    gemm_mfma<HD><<<GB, 256, 0, stream>>>(ahi, alo, w1h, w1l, b1, att1, hb1, bw, N);
    gather_kernel<true><<<N / 4, 256, 0, stream>>>(hb1, rp, col, bw, gamma, beta,
                                                   out, nullptr, nullptr);
}